// Round 1
// 131.890 us; speedup vs baseline: 1.0043x; 1.0043x over previous
//
#include <hip/hip_runtime.h>
#include <hip/hip_fp16.h>

// SAGEConv mean-aggr: out_i = mean_{j->i} x_j @ W_l^T + b_l + x_i @ W_r^T
//
// R1: global fp32 atomics write through L2 -> 300 MB, 481 us. Dead end.
// R2: 49x redundant dst-scan, latency-bound -> 365 us.
// R3: counting-sort by dst-bucket + LDS fp-atomic agg -> 200 us.
// R4: fp32 LDS atomicAdd is a CAS loop on gfx950 - never use it.
// R5: fixed-point u64 LDS atomics (native ds_add_u64) -> 141.7 us.
// R6: LDS weight staging regressed (8.2M 4-way bank conflicts, unpaddable).
// R7: persistent cooperative kernel regressed hard (322 us). Reverted.
// R8: weights hoisted to VGPRs (80/thread), 4 nodes/group -> 135.3 us.
// R9: proj 8 nodes/group branch-free; agg 512x196x512thr -> 132.45 us.
// R10: hl (the gathered projection) stored as 8xfp16 in 16 B rows:
//      agg gather 2 VMEM insts/edge -> 1 dwordx4/edge (TA request volume
//      halved), hl footprint 3.2 MB -> 1.6 MB (L2-resident vs the 7.9 MB
//      sorted stream), proj hl-write traffic halved. hr stays fp32 so the
//      exact self-term carries no fp16 noise; only the aggregated mean
//      gains <=2.4e-3 abs error.

#define N_NODES 100000
#define N_EDGES 1600000
#define D_IN 128

#define HR_STRIDE 8
#define N_PAD 100352                   // padded node count for clamp-free writes

#define B_NODES 196                    // nodes per bucket
#define N_BUCKETS 512                  // 512*196 = 100352 >= N_NODES
#define CAP 3840                       // mean 3125, sigma ~56 -> +12.8 sigma

#define SC_EPT 8
#define SC_EPB (256 * SC_EPT)          // 2048 edges per scatter block
#define SC_GRID ((N_EDGES + SC_EPB - 1) / SC_EPB)   // 782

#define NPG 8                          // nodes per 16-lane group
#define PROJ_NPB (16 * NPG)            // 128 nodes per proj block
#define PROJ_BLOCKS ((N_NODES + PROJ_NPB - 1) / PROJ_NPB)   // 782
#define FUSED_GRID (PROJ_BLOCKS + SC_GRID)                  // 1564

// fixed-point params for integer LDS accumulation
// per-addend field: f*2^18 + 2^24; deg<=116 keeps field sums < 2^31
#define FXS 262144.0f                  // 2^18 scale
#define FXB 16777216u                  // 2^24 bias per addend
#define FXBF 16777216.0f
#define INV_FXS (1.0f / 262144.0f)

typedef unsigned long long u64;
typedef unsigned int u32;

// ---------------------------------------------------------------------------
// Fused kernel A: blocks [0, PROJ_BLOCKS) projection; rest counting-sort
// scatter.
// ---------------------------------------------------------------------------
__global__ __launch_bounds__(256, 4) void proj_scatter_kernel(
    const float* __restrict__ x,
    const float* __restrict__ Wl,
    const float* __restrict__ Wr,
    uint4* __restrict__ hl,             // [N_PAD] 8xfp16 packed, first 5 valid
    float* __restrict__ hr,             // [N_PAD][8] f32, first 5 valid
    const int* __restrict__ ei,         // [2][N_EDGES]: row0 src, row1 dst
    u32* __restrict__ sorted,           // [N_BUCKETS][CAP]
    int* __restrict__ cursor)           // [N_BUCKETS], zero-initialized
{
    const int tid = threadIdx.x;

    if (blockIdx.x < PROJ_BLOCKS) {
        // ---------------- projection ----------------
        const int g = tid >> 4;          // group 0..15
        const int k = tid & 15;          // lane within group, dims [8k,8k+8)

        // hoist weights into registers: 10 rows x 8 floats = 80 VGPRs
        float4 wv[10][2];
#pragma unroll
        for (int o = 0; o < 10; ++o) {
            const float* w = (o < 5 ? Wl + o * D_IN : Wr + (o - 5) * D_IN) + k * 8;
            wv[o][0] = ((const float4*)w)[0];
            wv[o][1] = ((const float4*)w)[1];
        }

        const int node0 = blockIdx.x * PROJ_NPB + g * NPG;

#pragma unroll
        for (int it = 0; it < NPG; ++it) {
            // branch-free clamp: nodes >= N_NODES recompute row N_NODES-1 and
            // overwrite it with identical values (idempotent, no divergence)
            const int node = min(node0 + it, N_NODES - 1);

            const float4* xr = (const float4*)(x + (size_t)node * D_IN + k * 8);
            float4 x0 = xr[0];
            float4 x1 = xr[1];

            float s[10];
#pragma unroll
            for (int o = 0; o < 10; ++o) {
                s[o] = x0.x * wv[o][0].x + x0.y * wv[o][0].y
                     + x0.z * wv[o][0].z + x0.w * wv[o][0].w
                     + x1.x * wv[o][1].x + x1.y * wv[o][1].y
                     + x1.z * wv[o][1].z + x1.w * wv[o][1].w;
            }

#pragma unroll
            for (int o = 0; o < 10; ++o) {
                s[o] += __shfl_xor(s[o], 8, 64);
                s[o] += __shfl_xor(s[o], 4, 64);
                s[o] += __shfl_xor(s[o], 2, 64);
                s[o] += __shfl_xor(s[o], 1, 64);
            }

            if (k == 0) {
                // pack the 5 aggregated-projection values as fp16 into 16 B
                u32 u0 = (u32)__half_as_ushort(__float2half_rn(s[0]));
                u32 u1 = (u32)__half_as_ushort(__float2half_rn(s[1]));
                u32 u2 = (u32)__half_as_ushort(__float2half_rn(s[2]));
                u32 u3 = (u32)__half_as_ushort(__float2half_rn(s[3]));
                u32 u4 = (u32)__half_as_ushort(__float2half_rn(s[4]));
                uint4 pk;
                pk.x = u0 | (u1 << 16);
                pk.y = u2 | (u3 << 16);
                pk.z = u4;
                pk.w = 0u;
                hl[node] = pk;

                float* pr = hr + (size_t)node * HR_STRIDE;
                *(float4*)pr = make_float4(s[5], s[6], s[7], s[8]);
                pr[4] = s[9];
            }
        }
    } else {
        // ---------------- counting-sort scatter ----------------
        __shared__ int hist[N_BUCKETS];
        __shared__ int basepos[N_BUCKETS];

        for (int i = tid; i < N_BUCKETS; i += 256) hist[i] = 0;
        __syncthreads();

        const int blk = blockIdx.x - PROJ_BLOCKS;
        const int e0  = blk * SC_EPB + tid * SC_EPT;

        int srcv[SC_EPT], dstv[SC_EPT], slot[SC_EPT];
        bool valid[SC_EPT];

        if (e0 + SC_EPT <= N_EDGES) {
            const int4* s4 = (const int4*)(ei + e0);
            const int4* d4 = (const int4*)(ei + N_EDGES + e0);
            int4 sa = s4[0], sb = s4[1], da = d4[0], db = d4[1];
            srcv[0]=sa.x; srcv[1]=sa.y; srcv[2]=sa.z; srcv[3]=sa.w;
            srcv[4]=sb.x; srcv[5]=sb.y; srcv[6]=sb.z; srcv[7]=sb.w;
            dstv[0]=da.x; dstv[1]=da.y; dstv[2]=da.z; dstv[3]=da.w;
            dstv[4]=db.x; dstv[5]=db.y; dstv[6]=db.z; dstv[7]=db.w;
#pragma unroll
            for (int q = 0; q < SC_EPT; ++q) valid[q] = true;
        } else {
#pragma unroll
            for (int q = 0; q < SC_EPT; ++q) {
                int e = e0 + q;
                valid[q] = (e < N_EDGES);
                srcv[q] = valid[q] ? ei[e] : 0;
                dstv[q] = valid[q] ? ei[N_EDGES + e] : 0;
            }
        }

#pragma unroll
        for (int q = 0; q < SC_EPT; ++q) {
            if (valid[q]) {
                unsigned b = (unsigned)dstv[q] / 196u;   // magic-mul div
                slot[q] = atomicAdd(&hist[b], 1);
            }
        }
        __syncthreads();

        for (int b = tid; b < N_BUCKETS; b += 256) {
            int c = hist[b];
            if (c > 0) basepos[b] = atomicAdd(&cursor[b], c);
        }
        __syncthreads();

#pragma unroll
        for (int q = 0; q < SC_EPT; ++q) {
            if (valid[q]) {
                unsigned b = (unsigned)dstv[q] / 196u;
                unsigned r = (unsigned)dstv[q] - b * 196u;
                sorted[(size_t)b * CAP + basepos[b] + slot[q]] =
                    (r << 17) | (unsigned)srcv[q];
            }
        }
    }
}

// ---------------------------------------------------------------------------
// Kernel B: per-bucket aggregation via native u64 LDS atomics, fixed-point
// biased fields. 512 blocks x 512 threads = exactly 2 blocks/CU.
// Gather is now ONE dwordx4 per edge (8xfp16 hl row).
// ---------------------------------------------------------------------------
__global__ __launch_bounds__(512) void agg_kernel(
    const u32* __restrict__ sorted,
    const int* __restrict__ cursor,
    const uint4* __restrict__ hl,
    const float* __restrict__ hr,
    const float* __restrict__ bias,
    float* __restrict__ out)
{
    __shared__ u64 acc[B_NODES * 3];   // 4.7 KB

    const int b   = blockIdx.x;
    const int tid = threadIdx.x;

    for (int i = tid; i < B_NODES * 3; i += 512) acc[i] = 0ull;
    __syncthreads();

    const int cnt = cursor[b];
    const u32* sp = sorted + (size_t)b * CAP;
    const int nvec = cnt >> 2;

#define EMITH(hv, rr)                                                        \
    {                                                                        \
        float g0 = __half2float(__ushort_as_half((unsigned short)((hv).x & 0xFFFFu))); \
        float g1 = __half2float(__ushort_as_half((unsigned short)((hv).x >> 16)));     \
        float g2 = __half2float(__ushort_as_half((unsigned short)((hv).y & 0xFFFFu))); \
        float g3 = __half2float(__ushort_as_half((unsigned short)((hv).y >> 16)));     \
        float g4 = __half2float(__ushort_as_half((unsigned short)((hv).z & 0xFFFFu))); \
        u32 f0 = __float2uint_rn(fmaf(g0, FXS, FXBF));                       \
        u32 f1 = __float2uint_rn(fmaf(g1, FXS, FXBF));                       \
        u32 f2 = __float2uint_rn(fmaf(g2, FXS, FXBF));                       \
        u32 f3 = __float2uint_rn(fmaf(g3, FXS, FXBF));                       \
        u32 f4 = __float2uint_rn(fmaf(g4, FXS, FXBF));                       \
        u64* a = acc + (rr) * 3;                                             \
        atomicAdd(&a[0], ((u64)f1 << 32) | f0);                              \
        atomicAdd(&a[1], ((u64)f3 << 32) | f2);                              \
        atomicAdd(&a[2], ((u64)f4 << 32) | 1u);                              \
    }

    for (int it = tid; it < nvec; it += 512) {
        uint4 v = ((const uint4*)sp)[it];
        int s0 = (int)(v.x & 0x1FFFFu), r0 = (int)(v.x >> 17);
        int s1 = (int)(v.y & 0x1FFFFu), r1 = (int)(v.y >> 17);
        int s2 = (int)(v.z & 0x1FFFFu), r2 = (int)(v.z >> 17);
        int s3 = (int)(v.w & 0x1FFFFu), r3 = (int)(v.w >> 17);

        uint4 a0 = hl[s0];
        uint4 a1 = hl[s1];
        uint4 a2 = hl[s2];
        uint4 a3 = hl[s3];

        EMITH(a0, r0) EMITH(a1, r1) EMITH(a2, r2) EMITH(a3, r3)
    }
    for (int i = (nvec << 2) + tid; i < cnt; i += 512) {
        u32 v = sp[i];
        int src = (int)(v & 0x1FFFFu);
        int r   = (int)(v >> 17);
        uint4 a = hl[src];
        EMITH(a, r)
    }
#undef EMITH
    __syncthreads();

    const int nodebase = b * B_NODES;
    for (int n = tid; n < B_NODES; n += 512) {
        int node = nodebase + n;
        if (node >= N_NODES) continue;
        u64 w0 = acc[n * 3 + 0];
        u64 w1 = acc[n * 3 + 1];
        u64 w2 = acc[n * 3 + 2];
        u32 deg = (u32)(w2 & 0xFFFFFFFFu);
        u32 db  = deg * FXB;            // wraparound-safe: true values fit i32
        int i0 = (int)((u32)(w0 & 0xFFFFFFFFu) - db);
        int i1 = (int)((u32)(w0 >> 32)         - db);
        int i2 = (int)((u32)(w1 & 0xFFFFFFFFu) - db);
        int i3 = (int)((u32)(w1 >> 32)         - db);
        int i4 = (int)((u32)(w2 >> 32)         - db);

        float rec = INV_FXS / fmaxf((float)deg, 1.0f);
        const float* h = hr + (size_t)node * HR_STRIDE;
        float* o = out + (size_t)node * 5;
        o[0] = (float)i0 * rec + bias[0] + h[0];
        o[1] = (float)i1 * rec + bias[1] + h[1];
        o[2] = (float)i2 * rec + bias[2] + h[2];
        o[3] = (float)i3 * rec + bias[3] + h[3];
        o[4] = (float)i4 * rec + bias[4] + h[4];
    }
}

extern "C" void kernel_launch(void* const* d_in, const int* in_sizes, int n_in,
                              void* d_out, int out_size, void* d_ws, size_t ws_size,
                              hipStream_t stream) {
    const float* x    = (const float*)d_in[0];
    const int*   ei   = (const int*)d_in[1];
    const float* Wl   = (const float*)d_in[2];
    const float* bl   = (const float*)d_in[3];
    const float* Wr   = (const float*)d_in[4];
    float*       out  = (float*)d_out;

    // workspace layout (16B-aligned): ~12.7 MB total
    uint4* hl     = (uint4*)d_ws;                                 // N_PAD*16 B
    float* hr     = (float*)(hl + N_PAD);                         // N_PAD*8 f
    u32*   sorted = (u32*)(hr + (size_t)N_PAD * HR_STRIDE);       // 512*3840 u32
    int*   cursor = (int*)(sorted + (size_t)N_BUCKETS * CAP);     // 512 i32

    hipMemsetAsync(cursor, 0, N_BUCKETS * sizeof(int), stream);

    proj_scatter_kernel<<<FUSED_GRID, 256, 0, stream>>>(
        x, Wl, Wr, hl, hr, ei, sorted, cursor);

    agg_kernel<<<N_BUCKETS, 512, 0, stream>>>(sorted, cursor, hl, hr, bl, out);
}

// Round 2
// 127.673 us; speedup vs baseline: 1.0374x; 1.0330x over previous
//
#include <hip/hip_runtime.h>
#include <hip/hip_fp16.h>

// SAGEConv mean-aggr: out_i = mean_{j->i} x_j @ W_l^T + b_l + x_i @ W_r^T
//
// R1: global fp32 atomics write through L2 -> 300 MB, 481 us. Dead end.
// R2: 49x redundant dst-scan, latency-bound -> 365 us.
// R3: counting-sort by dst-bucket + LDS fp-atomic agg -> 200 us.
// R4: fp32 LDS atomicAdd is a CAS loop on gfx950 - never use it.
// R5: fixed-point u64 LDS atomics (native ds_add_u64) -> 141.7 us.
// R6: LDS weight staging regressed (8.2M 4-way bank conflicts, unpaddable).
// R7: persistent cooperative kernel regressed hard (322 us). Reverted.
// R8: weights hoisted to VGPRs (80/thread), 4 nodes/group -> 135.3 us.
// R9: proj 8 nodes/group branch-free; agg 512x196x512thr -> 132.45 us.
// R10: hl as 8xfp16 (1 dwordx4/edge gather) -> neutral (131.9). agg not pole.
//      Counters exposed proj_scatter: 41.4 us, VALU 9.6%, VGPR=60 (!),
//      1.5 TB/s vs 63 MB moved -> latency-bound; compiler demoted the 80
//      weight VGPRs and issues x loads just-in-time. FETCH 31 MB = 61% of
//      x misses L3 (poison fill evicts it) -> ~900 cyc exposed per iter.
// R11: (a) proj: prefetch-all-8-x-rows into regs FIRST, then two weight
//          passes (Wl, Wr: 5 rows = 40 VGPR live) over 4-node halves;
//          peak ~110 VGPR < 128 cap -> weights stay resident, 8 HBM loads
//          in flight per wave. Identical numerics.
//      (b) scatter: EPT 8->16 (391 blocks) -> cursor same-address atomics
//          halved, 2x per-thread ILP.
//      (c) 2:1 blockIdx interleave of proj/scatter so both phases co-reside.

#define N_NODES 100000
#define N_EDGES 1600000
#define D_IN 128

#define HR_STRIDE 8
#define N_PAD 100352                   // padded node count

#define B_NODES 196                    // nodes per bucket
#define N_BUCKETS 512                  // 512*196 = 100352 >= N_NODES
#define CAP 3840                       // mean 3125, sigma ~56 -> +12.8 sigma

#define SC_EPT 16
#define SC_EPB (256 * SC_EPT)          // 4096 edges per scatter block
#define SC_GRID ((N_EDGES + SC_EPB - 1) / SC_EPB)   // 391

#define NPG 8                          // nodes per 16-lane group
#define PROJ_NPB (16 * NPG)            // 128 nodes per proj block
#define PROJ_BLOCKS ((N_NODES + PROJ_NPB - 1) / PROJ_NPB)   // 782
// interleave 2 proj : 1 scatter; PROJ_BLOCKS == 2*SC_GRID == 782
#define FUSED_GRID (PROJ_BLOCKS + SC_GRID)                  // 1173

// fixed-point params for integer LDS accumulation
#define FXS 262144.0f                  // 2^18 scale
#define FXB 16777216u                  // 2^24 bias per addend
#define FXBF 16777216.0f
#define INV_FXS (1.0f / 262144.0f)

typedef unsigned long long u64;
typedef unsigned int u32;

__device__ __forceinline__ float dot8(const float4 a0, const float4 a1,
                                      const float4 b0, const float4 b1) {
    return a0.x * b0.x + a0.y * b0.y + a0.z * b0.z + a0.w * b0.w
         + a1.x * b1.x + a1.y * b1.y + a1.z * b1.z + a1.w * b1.w;
}

// ---------------------------------------------------------------------------
// Fused kernel A: interleaved projection (2 of 3 blocks) + counting-sort
// scatter (1 of 3).
// ---------------------------------------------------------------------------
__global__ __launch_bounds__(256, 4) void proj_scatter_kernel(
    const float* __restrict__ x,
    const float* __restrict__ Wl,
    const float* __restrict__ Wr,
    uint4* __restrict__ hl,             // [N_PAD] 8xfp16 packed, first 5 valid
    float* __restrict__ hr,             // [N_PAD][8] f32, first 5 valid
    const int* __restrict__ ei,         // [2][N_EDGES]: row0 src, row1 dst
    u32* __restrict__ sorted,           // [N_BUCKETS][CAP]
    int* __restrict__ cursor)           // [N_BUCKETS], zero-initialized
{
    const int tid = threadIdx.x;
    const int m   = blockIdx.x % 3;
    const int d   = blockIdx.x / 3;

    if (m < 2) {
        // ---------------- projection ----------------
        const int pidx = d * 2 + m;      // 0..781
        const int g = tid >> 4;          // group 0..15
        const int k = tid & 15;          // lane within group, dims [8k,8k+8)
        const int node0 = pidx * PROJ_NPB + g * NPG;

#pragma unroll
        for (int hb = 0; hb < 2; ++hb) {
            const int nb = node0 + hb * 4;

            // phase 1: issue ALL x loads (HBM latency) before anything else
            float4 xv[4][2];
            int nodes[4];
#pragma unroll
            for (int it = 0; it < 4; ++it) {
                // branch-free clamp: rows >= N_NODES recompute row N_NODES-1
                nodes[it] = min(nb + it, N_NODES - 1);
                const float4* xr =
                    (const float4*)(x + (size_t)nodes[it] * D_IN + k * 8);
                xv[it][0] = xr[0];
                xv[it][1] = xr[1];
            }

            // phase 2a: Wl pass (5 rows = 40 VGPR live)
            {
                float4 wv[5][2];
#pragma unroll
                for (int o = 0; o < 5; ++o) {
                    const float* w = Wl + o * D_IN + k * 8;
                    wv[o][0] = ((const float4*)w)[0];
                    wv[o][1] = ((const float4*)w)[1];
                }
#pragma unroll
                for (int it = 0; it < 4; ++it) {
                    float s[5];
#pragma unroll
                    for (int o = 0; o < 5; ++o)
                        s[o] = dot8(xv[it][0], xv[it][1], wv[o][0], wv[o][1]);
#pragma unroll
                    for (int o = 0; o < 5; ++o) {
                        s[o] += __shfl_xor(s[o], 8, 64);
                        s[o] += __shfl_xor(s[o], 4, 64);
                        s[o] += __shfl_xor(s[o], 2, 64);
                        s[o] += __shfl_xor(s[o], 1, 64);
                    }
                    if (k == 0) {
                        u32 u0 = (u32)__half_as_ushort(__float2half_rn(s[0]));
                        u32 u1 = (u32)__half_as_ushort(__float2half_rn(s[1]));
                        u32 u2 = (u32)__half_as_ushort(__float2half_rn(s[2]));
                        u32 u3 = (u32)__half_as_ushort(__float2half_rn(s[3]));
                        u32 u4 = (u32)__half_as_ushort(__float2half_rn(s[4]));
                        uint4 pk;
                        pk.x = u0 | (u1 << 16);
                        pk.y = u2 | (u3 << 16);
                        pk.z = u4;
                        pk.w = 0u;
                        hl[nodes[it]] = pk;
                    }
                }
            }

            // phase 2b: Wr pass
            {
                float4 wv[5][2];
#pragma unroll
                for (int o = 0; o < 5; ++o) {
                    const float* w = Wr + o * D_IN + k * 8;
                    wv[o][0] = ((const float4*)w)[0];
                    wv[o][1] = ((const float4*)w)[1];
                }
#pragma unroll
                for (int it = 0; it < 4; ++it) {
                    float s[5];
#pragma unroll
                    for (int o = 0; o < 5; ++o)
                        s[o] = dot8(xv[it][0], xv[it][1], wv[o][0], wv[o][1]);
#pragma unroll
                    for (int o = 0; o < 5; ++o) {
                        s[o] += __shfl_xor(s[o], 8, 64);
                        s[o] += __shfl_xor(s[o], 4, 64);
                        s[o] += __shfl_xor(s[o], 2, 64);
                        s[o] += __shfl_xor(s[o], 1, 64);
                    }
                    if (k == 0) {
                        float* pr = hr + (size_t)nodes[it] * HR_STRIDE;
                        *(float4*)pr = make_float4(s[0], s[1], s[2], s[3]);
                        pr[4] = s[4];
                    }
                }
            }
        }
    } else {
        // ---------------- counting-sort scatter ----------------
        __shared__ int hist[N_BUCKETS];
        __shared__ int basepos[N_BUCKETS];

        for (int i = tid; i < N_BUCKETS; i += 256) hist[i] = 0;
        __syncthreads();

        const int e0 = d * SC_EPB + tid * SC_EPT;

        int srcv[SC_EPT], dstv[SC_EPT], slot[SC_EPT];
        bool valid[SC_EPT];

        if (e0 + SC_EPT <= N_EDGES) {
            const int4* s4 = (const int4*)(ei + e0);
            const int4* d4 = (const int4*)(ei + N_EDGES + e0);
#pragma unroll
            for (int c = 0; c < SC_EPT / 4; ++c) {
                int4 sv = s4[c], dv = d4[c];
                srcv[c*4+0] = sv.x; srcv[c*4+1] = sv.y;
                srcv[c*4+2] = sv.z; srcv[c*4+3] = sv.w;
                dstv[c*4+0] = dv.x; dstv[c*4+1] = dv.y;
                dstv[c*4+2] = dv.z; dstv[c*4+3] = dv.w;
            }
#pragma unroll
            for (int q = 0; q < SC_EPT; ++q) valid[q] = true;
        } else {
#pragma unroll
            for (int q = 0; q < SC_EPT; ++q) {
                int e = e0 + q;
                valid[q] = (e < N_EDGES);
                srcv[q] = valid[q] ? ei[e] : 0;
                dstv[q] = valid[q] ? ei[N_EDGES + e] : 0;
            }
        }

#pragma unroll
        for (int q = 0; q < SC_EPT; ++q) {
            if (valid[q]) {
                unsigned b = (unsigned)dstv[q] / 196u;   // magic-mul div
                slot[q] = atomicAdd(&hist[b], 1);
            }
        }
        __syncthreads();

        for (int b = tid; b < N_BUCKETS; b += 256) {
            int c = hist[b];
            if (c > 0) basepos[b] = atomicAdd(&cursor[b], c);
        }
        __syncthreads();

#pragma unroll
        for (int q = 0; q < SC_EPT; ++q) {
            if (valid[q]) {
                unsigned b = (unsigned)dstv[q] / 196u;
                unsigned r = (unsigned)dstv[q] - b * 196u;
                sorted[(size_t)b * CAP + basepos[b] + slot[q]] =
                    (r << 17) | (unsigned)srcv[q];
            }
        }
    }
}

// ---------------------------------------------------------------------------
// Kernel B: per-bucket aggregation via native u64 LDS atomics, fixed-point
// biased fields. 512 blocks x 512 threads = exactly 2 blocks/CU.
// ---------------------------------------------------------------------------
__global__ __launch_bounds__(512) void agg_kernel(
    const u32* __restrict__ sorted,
    const int* __restrict__ cursor,
    const uint4* __restrict__ hl,
    const float* __restrict__ hr,
    const float* __restrict__ bias,
    float* __restrict__ out)
{
    __shared__ u64 acc[B_NODES * 3];   // 4.7 KB

    const int b   = blockIdx.x;
    const int tid = threadIdx.x;

    for (int i = tid; i < B_NODES * 3; i += 512) acc[i] = 0ull;
    __syncthreads();

    const int cnt = cursor[b];
    const u32* sp = sorted + (size_t)b * CAP;
    const int nvec = cnt >> 2;

#define EMITH(hv, rr)                                                        \
    {                                                                        \
        float g0 = __half2float(__ushort_as_half((unsigned short)((hv).x & 0xFFFFu))); \
        float g1 = __half2float(__ushort_as_half((unsigned short)((hv).x >> 16)));     \
        float g2 = __half2float(__ushort_as_half((unsigned short)((hv).y & 0xFFFFu))); \
        float g3 = __half2float(__ushort_as_half((unsigned short)((hv).y >> 16)));     \
        float g4 = __half2float(__ushort_as_half((unsigned short)((hv).z & 0xFFFFu))); \
        u32 f0 = __float2uint_rn(fmaf(g0, FXS, FXBF));                       \
        u32 f1 = __float2uint_rn(fmaf(g1, FXS, FXBF));                       \
        u32 f2 = __float2uint_rn(fmaf(g2, FXS, FXBF));                       \
        u32 f3 = __float2uint_rn(fmaf(g3, FXS, FXBF));                       \
        u32 f4 = __float2uint_rn(fmaf(g4, FXS, FXBF));                       \
        u64* a = acc + (rr) * 3;                                             \
        atomicAdd(&a[0], ((u64)f1 << 32) | f0);                              \
        atomicAdd(&a[1], ((u64)f3 << 32) | f2);                              \
        atomicAdd(&a[2], ((u64)f4 << 32) | 1u);                              \
    }

    for (int it = tid; it < nvec; it += 512) {
        uint4 v = ((const uint4*)sp)[it];
        int s0 = (int)(v.x & 0x1FFFFu), r0 = (int)(v.x >> 17);
        int s1 = (int)(v.y & 0x1FFFFu), r1 = (int)(v.y >> 17);
        int s2 = (int)(v.z & 0x1FFFFu), r2 = (int)(v.z >> 17);
        int s3 = (int)(v.w & 0x1FFFFu), r3 = (int)(v.w >> 17);

        uint4 a0 = hl[s0];
        uint4 a1 = hl[s1];
        uint4 a2 = hl[s2];
        uint4 a3 = hl[s3];

        EMITH(a0, r0) EMITH(a1, r1) EMITH(a2, r2) EMITH(a3, r3)
    }
    for (int i = (nvec << 2) + tid; i < cnt; i += 512) {
        u32 v = sp[i];
        int src = (int)(v & 0x1FFFFu);
        int r   = (int)(v >> 17);
        uint4 a = hl[src];
        EMITH(a, r)
    }
#undef EMITH
    __syncthreads();

    const int nodebase = b * B_NODES;
    for (int n = tid; n < B_NODES; n += 512) {
        int node = nodebase + n;
        if (node >= N_NODES) continue;
        u64 w0 = acc[n * 3 + 0];
        u64 w1 = acc[n * 3 + 1];
        u64 w2 = acc[n * 3 + 2];
        u32 deg = (u32)(w2 & 0xFFFFFFFFu);
        u32 db  = deg * FXB;            // wraparound-safe: true values fit i32
        int i0 = (int)((u32)(w0 & 0xFFFFFFFFu) - db);
        int i1 = (int)((u32)(w0 >> 32)         - db);
        int i2 = (int)((u32)(w1 & 0xFFFFFFFFu) - db);
        int i3 = (int)((u32)(w1 >> 32)         - db);
        int i4 = (int)((u32)(w2 >> 32)         - db);

        float rec = INV_FXS / fmaxf((float)deg, 1.0f);
        const float* h = hr + (size_t)node * HR_STRIDE;
        float* o = out + (size_t)node * 5;
        o[0] = (float)i0 * rec + bias[0] + h[0];
        o[1] = (float)i1 * rec + bias[1] + h[1];
        o[2] = (float)i2 * rec + bias[2] + h[2];
        o[3] = (float)i3 * rec + bias[3] + h[3];
        o[4] = (float)i4 * rec + bias[4] + h[4];
    }
}

extern "C" void kernel_launch(void* const* d_in, const int* in_sizes, int n_in,
                              void* d_out, int out_size, void* d_ws, size_t ws_size,
                              hipStream_t stream) {
    const float* x    = (const float*)d_in[0];
    const int*   ei   = (const int*)d_in[1];
    const float* Wl   = (const float*)d_in[2];
    const float* bl   = (const float*)d_in[3];
    const float* Wr   = (const float*)d_in[4];
    float*       out  = (float*)d_out;

    // workspace layout (16B-aligned): ~12.7 MB total
    uint4* hl     = (uint4*)d_ws;                                 // N_PAD*16 B
    float* hr     = (float*)(hl + N_PAD);                         // N_PAD*8 f
    u32*   sorted = (u32*)(hr + (size_t)N_PAD * HR_STRIDE);       // 512*3840 u32
    int*   cursor = (int*)(sorted + (size_t)N_BUCKETS * CAP);     // 512 i32

    hipMemsetAsync(cursor, 0, N_BUCKETS * sizeof(int), stream);

    proj_scatter_kernel<<<FUSED_GRID, 256, 0, stream>>>(
        x, Wl, Wr, hl, hr, ei, sorted, cursor);

    agg_kernel<<<N_BUCKETS, 512, 0, stream>>>(sorted, cursor, hl, hr, bl, out);
}